// Round 3
// baseline (456.226 us; speedup 1.0000x reference)
//
#include <hip/hip_runtime.h>
#include <math.h>

#define B 32
#define NH 32
#define NKV 8
#define GRP 4
#define HD 128
#define DIM 4096
#define NQKV 6144   // (NH + 2*NKV) * HD
#define WIN 4096
#define KS 32       // split-K chunks for the skinny GEMMs
#define SPLIT 8     // attention sequence chunks
#define SCHUNK (WIN / SPLIT)   // 512 positions per chunk

__device__ __forceinline__ float fast_exp2(float x) {
#if __has_builtin(__builtin_amdgcn_exp2f)
  return __builtin_amdgcn_exp2f(x);
#else
  return exp2f(x);
#endif
}

// ---------------------------------------------------------------------------
// Skinny GEMM: part[kc][b][f..f+1] = sum_{k in chunk kc} X[b][k] * W[k][f..f+1]
// X: [B][K], W: [K][N]. Grid (N/256, KS), block 128 (each lane owns 2 columns).
// Deterministic split-K. float2 W loads halve instruction count per byte.
// ---------------------------------------------------------------------------
__global__ __launch_bounds__(128)
void gemv32_partial(const float* __restrict__ X, const float* __restrict__ W,
                    float* __restrict__ part, int K, int N) {
  const int f  = (blockIdx.x * 128 + threadIdx.x) * 2;
  const int kc = blockIdx.y;
  const int kchunk = K / KS;   // 128 for both GEMMs
  const int k0 = kc * kchunk;

  // xs[kk][b], padded row to 36 floats (16B-aligned rows for float4 reads)
  __shared__ float xs[128][36];

  float acc0[B], acc1[B];
#pragma unroll
  for (int b = 0; b < B; ++b) { acc0[b] = 0.f; acc1[b] = 0.f; }

  for (int kb = 0; kb < kchunk; kb += 128) {
    __syncthreads();
    for (int idx = threadIdx.x; idx < B * 128; idx += 128) {
      int bb = idx >> 7;        // 0..31
      int kk = idx & 127;       // 0..127  (coalesced read from X)
      xs[kk][bb] = X[(size_t)bb * K + (k0 + kb + kk)];
    }
    __syncthreads();

    const float* wp = W + (size_t)(k0 + kb) * N + f;
#pragma unroll 8
    for (int kk = 0; kk < 128; ++kk) {
      float2 w2 = *(const float2*)(wp + (size_t)kk * N);   // coalesced 8B/lane
      const float4* xr = (const float4*)&xs[kk][0];        // broadcast reads
#pragma unroll
      for (int b4 = 0; b4 < 8; ++b4) {
        float4 xv = xr[b4];
        acc0[b4 * 4 + 0] += xv.x * w2.x;  acc1[b4 * 4 + 0] += xv.x * w2.y;
        acc0[b4 * 4 + 1] += xv.y * w2.x;  acc1[b4 * 4 + 1] += xv.y * w2.y;
        acc0[b4 * 4 + 2] += xv.z * w2.x;  acc1[b4 * 4 + 2] += xv.z * w2.y;
        acc0[b4 * 4 + 3] += xv.w * w2.x;  acc1[b4 * 4 + 3] += xv.w * w2.y;
      }
    }
  }

  float* pp = part + (size_t)kc * B * N + f;
#pragma unroll
  for (int b = 0; b < B; ++b) {
    float2 o; o.x = acc0[b]; o.y = acc1[b];
    *(float2*)(pp + (size_t)b * N) = o;
  }
}

// ---------------------------------------------------------------------------
// Reduce split-K partials: out[idx] = sum_kc part[kc][idx]
// ---------------------------------------------------------------------------
__global__ __launch_bounds__(256)
void reduce_partials(const float* __restrict__ part, float* __restrict__ out,
                     int total) {
  int idx = blockIdx.x * 256 + threadIdx.x;
  if (idx >= total) return;
  float s = 0.f;
#pragma unroll
  for (int kc = 0; kc < KS; ++kc) s += part[(size_t)kc * total + idx];
  out[idx] = s;
}

// ---------------------------------------------------------------------------
// Rotary: per (b, head) vector v (128), out[e] = sum_d v[d] * rot[d][e]
// heads 0..31 -> q, scaled by rsqrt(128)*log2(e) so exp2(q.k) == softmax arg;
// heads 32..39 -> k (unscaled).
// ---------------------------------------------------------------------------
__global__ __launch_bounds__(128)
void rotary_kernel(const float* __restrict__ xqkv, const float* __restrict__ rot,
                   float* __restrict__ qrot, float* __restrict__ krot) {
  const int b = blockIdx.x;
  const int h = blockIdx.y;   // 0..39
  const int e = threadIdx.x;  // 0..127

  __shared__ float vec[HD];
  vec[e] = xqkv[(size_t)b * NQKV + h * HD + e];
  __syncthreads();

  float s = 0.f;
#pragma unroll 8
  for (int d = 0; d < HD; ++d) s += vec[d] * rot[d * HD + e];

  const float QSCALE = 0.08838834764831845f * 1.4426950408889634f;
  if (h < NH) {
    qrot[((size_t)b * NH + h) * HD + e] = s * QSCALE;
  } else {
    krot[((size_t)b * NKV + (h - NH)) * HD + e] = s;
  }
}

// ---------------------------------------------------------------------------
// Flash-decode attention partial (fixed-base softmax, head-split lanes).
// Grid (B*NKV pairs, SPLIT chunks), block 256 (4 waves, 8 half-waves).
// Half-wave owns one position; within it lane = (head g = l32>>3, dim-chunk
// dc = l32&7, dims j*32+dc*4 for j=0..3). Score reduce = 3 shuffles (xor
// 1,2,4). Main loop runs on stale cache; new-token corrected after the loop.
// ---------------------------------------------------------------------------
__global__ __launch_bounds__(256)
void attn_partial(const float* __restrict__ cache_k, const float* __restrict__ cache_v,
                  const float* __restrict__ qrot, const float* __restrict__ krot,
                  const float* __restrict__ xqkv, const int* __restrict__ start_pos,
                  float* __restrict__ o_part, float* __restrict__ l_part) {
  const int pair = blockIdx.x;            // b * NKV + kvh
  const int b    = pair >> 3;
  const int kvh  = pair & 7;
  const int chunk = blockIdx.y;

  const int sp    = start_pos[0];
  const int cur   = sp & (WIN - 1);
  const int slice = (sp + 1 < WIN) ? (sp + 1) : WIN;

  const int tid  = threadIdx.x;
  const int wave = tid >> 6;
  const int lane = tid & 63;
  const int half = lane >> 5;
  const int l32  = lane & 31;
  const int g    = l32 >> 3;              // head within group, 0..3
  const int dc   = l32 & 7;               // dim chunk, 0..7
  const int hw   = wave * 2 + half;       // half-wave id 0..7

  // q fragments for my head: dims j*32 + dc*4 .. +4, j = 0..3
  float4 q[4];
  {
    const float* qp = qrot + ((size_t)(b * NH + kvh * GRP + g)) * HD + dc * 4;
#pragma unroll
    for (int j = 0; j < 4; ++j) q[j] = *(const float4*)(qp + j * 32);
  }

  const float4* kbase = (const float4*)(cache_k + ((size_t)(kvh * B + b)) * WIN * HD);
  const float4* vbase = (const float4*)(cache_v + ((size_t)(kvh * B + b)) * WIN * HD);

  float  l = 0.f;
  float4 acc[4] = {};

  const int s0 = chunk * SCHUNK;
  int rem = slice - s0 - hw;
  int n_i = rem <= 0 ? 0 : ((rem + 7) >> 3);
  if (n_i > SCHUNK / 8) n_i = SCHUNK / 8;

#pragma unroll 2
  for (int i = 0; i < n_i; ++i) {
    const int p = s0 + i * 8 + hw;
    const size_t rb = (size_t)p * 32 + dc;   // float4 index of my chunk, j=0
    float4 k0 = kbase[rb + 0],  k1 = kbase[rb + 8],
           k2 = kbase[rb + 16], k3 = kbase[rb + 24];
    float4 v0 = vbase[rb + 0],  v1 = vbase[rb + 8],
           v2 = vbase[rb + 16], v3 = vbase[rb + 24];

    float s = q[0].x * k0.x + q[0].y * k0.y + q[0].z * k0.z + q[0].w * k0.w
            + q[1].x * k1.x + q[1].y * k1.y + q[1].z * k1.z + q[1].w * k1.w
            + q[2].x * k2.x + q[2].y * k2.y + q[2].z * k2.z + q[2].w * k2.w
            + q[3].x * k3.x + q[3].y * k3.y + q[3].z * k3.z + q[3].w * k3.w;

    // reduce over the 8 dc-lanes of my head group
    s += __shfl_xor(s, 1);
    s += __shfl_xor(s, 2);
    s += __shfl_xor(s, 4);

    float w = fast_exp2(s);     // == exp(q.k/sqrt(128)); scale folded in q
    l += w;
    acc[0].x += w * v0.x; acc[0].y += w * v0.y; acc[0].z += w * v0.z; acc[0].w += w * v0.w;
    acc[1].x += w * v1.x; acc[1].y += w * v1.y; acc[1].z += w * v1.z; acc[1].w += w * v1.w;
    acc[2].x += w * v2.x; acc[2].y += w * v2.y; acc[2].z += w * v2.z; acc[2].w += w * v2.w;
    acc[3].x += w * v3.x; acc[3].y += w * v3.y; acc[3].z += w * v3.z; acc[3].w += w * v3.w;
  }

  // Correct the new-token position: subtract stale contribution, add new one.
  if (chunk == (cur >> 9) && hw == (cur & 7)) {
    const size_t rb = (size_t)cur * 32 + dc;
    const float* kp = krot + ((size_t)(b * NKV + kvh)) * HD + dc * 4;
    const float* vp = xqkv + (size_t)b * NQKV + (NH + NKV + kvh) * HD + dc * 4;
    float sst = 0.f, snw = 0.f;
    float4 kst[4], vst[4], knw[4], vnw[4];
#pragma unroll
    for (int j = 0; j < 4; ++j) {
      kst[j] = kbase[rb + j * 8];
      vst[j] = vbase[rb + j * 8];
      knw[j] = *(const float4*)(kp + j * 32);
      vnw[j] = *(const float4*)(vp + j * 32);
      sst += q[j].x * kst[j].x + q[j].y * kst[j].y + q[j].z * kst[j].z + q[j].w * kst[j].w;
      snw += q[j].x * knw[j].x + q[j].y * knw[j].y + q[j].z * knw[j].z + q[j].w * knw[j].w;
    }
    sst += __shfl_xor(sst, 1); sst += __shfl_xor(sst, 2); sst += __shfl_xor(sst, 4);
    snw += __shfl_xor(snw, 1); snw += __shfl_xor(snw, 2); snw += __shfl_xor(snw, 4);
    float wst = fast_exp2(sst);
    float wnw = fast_exp2(snw);
    l += wnw - wst;
#pragma unroll
    for (int j = 0; j < 4; ++j) {
      acc[j].x += wnw * vnw[j].x - wst * vst[j].x;
      acc[j].y += wnw * vnw[j].y - wst * vst[j].y;
      acc[j].z += wnw * vnw[j].z - wst * vst[j].z;
      acc[j].w += wnw * vnw[j].w - wst * vst[j].w;
    }
  }

  // combine the two halves of the wave (plain adds — fixed-base softmax)
  l += __shfl_xor(l, 32);
#pragma unroll
  for (int j = 0; j < 4; ++j) {
    acc[j].x += __shfl_xor(acc[j].x, 32);
    acc[j].y += __shfl_xor(acc[j].y, 32);
    acc[j].z += __shfl_xor(acc[j].z, 32);
    acc[j].w += __shfl_xor(acc[j].w, 32);
  }

  // combine the 4 waves via LDS
  __shared__ float red_l[4][GRP];
  __shared__ float red_o[4][GRP][HD];
  if (half == 0) {
#pragma unroll
    for (int j = 0; j < 4; ++j)
      *(float4*)&red_o[wave][g][j * 32 + dc * 4] = acc[j];
    if (dc == 0) red_l[wave][g] = l;
  }
  __syncthreads();

  const size_t pc = (size_t)pair * SPLIT + chunk;
  for (int idx = tid; idx < GRP * HD; idx += 256) {
    int gg = idx >> 7, d = idx & 127;
    float o = red_o[0][gg][d] + red_o[1][gg][d] + red_o[2][gg][d] + red_o[3][gg][d];
    o_part[(pc * GRP + gg) * HD + d] = o;
  }
  if (tid < GRP) {
    l_part[pc * GRP + tid] =
        red_l[0][tid] + red_l[1][tid] + red_l[2][tid] + red_l[3][tid];
  }
}

// ---------------------------------------------------------------------------
// Combine the SPLIT chunk partials -> attn_out[b][n*128 + d]
// Grid: B*NH blocks, 128 threads (one per d). Plain sums (fixed-base softmax).
// ---------------------------------------------------------------------------
__global__ __launch_bounds__(128)
void attn_combine(const float* __restrict__ o_part, const float* __restrict__ l_part,
                  float* __restrict__ attn_out) {
  const int bid = blockIdx.x;   // b*32 + n
  const int b = bid >> 5, n = bid & 31;
  const int pair = b * NKV + (n >> 2);
  const int g = n & 3;
  const int d = threadIdx.x;

  float lsum = 0.f, osum = 0.f;
#pragma unroll
  for (int c = 0; c < SPLIT; ++c) {
    size_t pc = (size_t)pair * SPLIT + c;
    lsum += l_part[pc * GRP + g];
    osum += o_part[(pc * GRP + g) * HD + d];
  }
  attn_out[(size_t)b * DIM + n * HD + d] = osum / lsum;
}

// ---------------------------------------------------------------------------
extern "C" void kernel_launch(void* const* d_in, const int* in_sizes, int n_in,
                              void* d_out, int out_size, void* d_ws, size_t ws_size,
                              hipStream_t stream) {
  (void)in_sizes; (void)n_in; (void)out_size; (void)ws_size;

  const float* x    = (const float*)d_in[0];  // [1,1,32,4096]
  const float* wqkv = (const float*)d_in[1];  // [4096,6144]
  const float* wo   = (const float*)d_in[2];  // [4096,4096]
  const float* rot  = (const float*)d_in[3];  // [128,128]
  const float* ck   = (const float*)d_in[4];  // [8,32,4096,128]
  const float* cv   = (const float*)d_in[5];  // [8,32,4096,128]
  const int*   sp   = (const int*)d_in[6];    // scalar
  float* out = (float*)d_out;                 // [32,4096]

  float* ws       = (float*)d_ws;
  float* part     = ws;                                    // KS*B*NQKV
  float* xqkv     = part + (size_t)KS * B * NQKV;
  float* qrot     = xqkv + (size_t)B * NQKV;
  float* krot     = qrot + (size_t)B * NH * HD;
  float* o_part   = krot + (size_t)B * NKV * HD;
  float* l_part   = o_part + (size_t)B * NKV * SPLIT * GRP * HD;
  float* attn_out = l_part + (size_t)B * NKV * SPLIT * GRP;

  // 1) xqkv = x @ wqkv  (split-K partials, then reduce)
  gemv32_partial<<<dim3(NQKV / 256, KS), 128, 0, stream>>>(x, wqkv, part, DIM, NQKV);
  reduce_partials<<<(B * NQKV) / 256, 256, 0, stream>>>(part, xqkv, B * NQKV);

  // 2) rotary on q (scaled; exp2 base folded in) and k
  rotary_kernel<<<dim3(B, NH + NKV), 128, 0, stream>>>(xqkv, rot, qrot, krot);

  // 3) flash-decode attention over the KV cache (stale loop + post-correction)
  attn_partial<<<dim3(B * NKV, SPLIT), 256, 0, stream>>>(ck, cv, qrot, krot, xqkv,
                                                         sp, o_part, l_part);
  attn_combine<<<B * NH, 128, 0, stream>>>(o_part, l_part, attn_out);

  // 4) dense = attn_out @ wo
  gemv32_partial<<<dim3(DIM / 256, KS), 128, 0, stream>>>(attn_out, wo, part, DIM, DIM);
  reduce_partials<<<(B * DIM) / 256, 256, 0, stream>>>(part, out, B * DIM);
}

// Round 4
// 317.577 us; speedup vs baseline: 1.4366x; 1.4366x over previous
//
#include <hip/hip_runtime.h>
#include <math.h>

#define B 32
#define NH 32
#define NKV 8
#define GRP 4
#define HD 128
#define DIM 4096
#define NQKV 6144   // (NH + 2*NKV) * HD
#define WIN 4096
#define KS 32       // split-K chunks for the skinny GEMMs
#define SPLIT 16    // attention sequence chunks
#define SCHUNK (WIN / SPLIT)   // 256 positions per chunk

__device__ __forceinline__ float fast_exp2(float x) {
#if __has_builtin(__builtin_amdgcn_exp2f)
  return __builtin_amdgcn_exp2f(x);
#else
  return exp2f(x);
#endif
}

// ---------------------------------------------------------------------------
// Skinny GEMM: part[kc][b][f] = sum_{k in chunk kc} X[b][k] * W[k][f]
// X: [B][K], W: [K][N]. Grid (N/256, KS), block 256. Deterministic split-K.
// (Exactly the R2 version — 12 waves/CU for wqkv keeps enough loads in
// flight; R3's 128-thread variant halved that and regressed.)
// ---------------------------------------------------------------------------
__global__ __launch_bounds__(256)
void gemv32_partial(const float* __restrict__ X, const float* __restrict__ W,
                    float* __restrict__ part, int K, int N) {
  const int f  = blockIdx.x * 256 + threadIdx.x;
  const int kc = blockIdx.y;
  const int kchunk = K / KS;
  const int k0 = kc * kchunk;

  __shared__ float xs[128][36];

  float acc[B];
#pragma unroll
  for (int b = 0; b < B; ++b) acc[b] = 0.f;

  for (int kb = 0; kb < kchunk; kb += 128) {
    __syncthreads();
    for (int idx = threadIdx.x; idx < B * 128; idx += 256) {
      int bb = idx >> 7;
      int kk = idx & 127;
      xs[kk][bb] = X[(size_t)bb * K + (k0 + kb + kk)];
    }
    __syncthreads();

    const float* wp = W + (size_t)(k0 + kb) * N + f;
#pragma unroll 4
    for (int kk = 0; kk < 128; ++kk) {
      float w = wp[(size_t)kk * N];
      const float4* xr = (const float4*)&xs[kk][0];
#pragma unroll
      for (int b4 = 0; b4 < 8; ++b4) {
        float4 xv = xr[b4];
        acc[b4 * 4 + 0] += xv.x * w;
        acc[b4 * 4 + 1] += xv.y * w;
        acc[b4 * 4 + 2] += xv.z * w;
        acc[b4 * 4 + 3] += xv.w * w;
      }
    }
  }

  float* pp = part + (size_t)kc * B * N + f;
#pragma unroll
  for (int b = 0; b < B; ++b) pp[(size_t)b * N] = acc[b];
}

// ---------------------------------------------------------------------------
// Reduce split-K partials: out[idx] = sum_kc part[kc][idx]
// ---------------------------------------------------------------------------
__global__ __launch_bounds__(256)
void reduce_partials(const float* __restrict__ part, float* __restrict__ out,
                     int total) {
  int idx = blockIdx.x * 256 + threadIdx.x;
  if (idx >= total) return;
  float s = 0.f;
#pragma unroll
  for (int kc = 0; kc < KS; ++kc) s += part[(size_t)kc * total + idx];
  out[idx] = s;
}

// ---------------------------------------------------------------------------
// Rotary: per (b, head) vector v (128), out[e] = sum_d v[d] * rot[d][e]
// q heads scaled by rsqrt(128)*log2(e) (fixed-base-2 softmax); k unscaled.
// ---------------------------------------------------------------------------
__global__ __launch_bounds__(128)
void rotary_kernel(const float* __restrict__ xqkv, const float* __restrict__ rot,
                   float* __restrict__ qrot, float* __restrict__ krot) {
  const int b = blockIdx.x;
  const int h = blockIdx.y;   // 0..39
  const int e = threadIdx.x;  // 0..127

  __shared__ float vec[HD];
  vec[e] = xqkv[(size_t)b * NQKV + h * HD + e];
  __syncthreads();

  float s = 0.f;
#pragma unroll 8
  for (int d = 0; d < HD; ++d) s += vec[d] * rot[d * HD + e];

  const float QSCALE = 0.08838834764831845f * 1.4426950408889634f;
  if (h < NH) {
    qrot[((size_t)b * NH + h) * HD + e] = s * QSCALE;
  } else {
    krot[((size_t)b * NKV + (h - NH)) * HD + e] = s;
  }
}

// ---------------------------------------------------------------------------
// Flash-decode attention partial (fixed-base softmax, R2 lane layout:
// half-wave of 32 lanes owns a position, lane holds dims l32*4..+3).
// Explicit 2-deep prefetch. Stale-cache loop + one-shot new-token correction.
// Grid (B*NKV, SPLIT), block 256.
// ---------------------------------------------------------------------------
__global__ __launch_bounds__(256)
void attn_partial(const float* __restrict__ cache_k, const float* __restrict__ cache_v,
                  const float* __restrict__ qrot, const float* __restrict__ krot,
                  const float* __restrict__ xqkv, const int* __restrict__ start_pos,
                  float* __restrict__ o_part, float* __restrict__ l_part) {
  const int pair = blockIdx.x;            // b * NKV + kvh
  const int b    = pair >> 3;
  const int kvh  = pair & 7;
  const int chunk = blockIdx.y;

  const int sp    = start_pos[0];
  const int cur   = sp & (WIN - 1);
  const int slice = (sp + 1 < WIN) ? (sp + 1) : WIN;

  const int tid  = threadIdx.x;
  const int wave = tid >> 6;
  const int lane = tid & 63;
  const int half = lane >> 5;
  const int l32  = lane & 31;
  const int hw   = wave * 2 + half;       // half-wave id 0..7

  float4 q[GRP];
#pragma unroll
  for (int g = 0; g < GRP; ++g)
    q[g] = *(const float4*)(qrot + ((size_t)(b * NH + kvh * GRP + g)) * HD + l32 * 4);

  const float4* kbase = (const float4*)(cache_k + ((size_t)(kvh * B + b)) * WIN * HD);
  const float4* vbase = (const float4*)(cache_v + ((size_t)(kvh * B + b)) * WIN * HD);

  float  l[GRP] = {0.f, 0.f, 0.f, 0.f};
  float4 acc[GRP] = {};

  const int s0 = chunk * SCHUNK;
  int rem = slice - s0 - hw;
  int n_i = rem <= 0 ? 0 : ((rem + 7) >> 3);
  if (n_i > SCHUNK / 8) n_i = SCHUNK / 8;

  auto body = [&](float4 k4, float4 v4) {
    float s[GRP];
#pragma unroll
    for (int g = 0; g < GRP; ++g)
      s[g] = q[g].x * k4.x + q[g].y * k4.y + q[g].z * k4.z + q[g].w * k4.w;
#pragma unroll
    for (int off = 16; off > 0; off >>= 1) {
#pragma unroll
      for (int g = 0; g < GRP; ++g) s[g] += __shfl_xor(s[g], off);
    }
#pragma unroll
    for (int g = 0; g < GRP; ++g) {
      float w = fast_exp2(s[g]);          // == exp(q.k/sqrt(128))
      l[g] += w;
      acc[g].x += w * v4.x; acc[g].y += w * v4.y;
      acc[g].z += w * v4.z; acc[g].w += w * v4.w;
    }
  };

  if (n_i > 0) {
    size_t rb = ((size_t)(s0 + hw)) * 32 + l32;
    float4 k4 = kbase[rb];
    float4 v4 = vbase[rb];
#pragma unroll 2
    for (int i = 1; i < n_i; ++i) {
      rb += 8 * 32;
      float4 kn = kbase[rb];
      float4 vn = vbase[rb];
      body(k4, v4);
      k4 = kn; v4 = vn;
    }
    body(k4, v4);
  }

  // Correct the new-token position: subtract stale contribution, add new one.
  if (chunk == (cur >> 8) && hw == (cur & 7)) {
    float4 kst = kbase[(size_t)cur * 32 + l32];
    float4 vst = vbase[(size_t)cur * 32 + l32];
    const float4 knew = *(const float4*)(krot + ((size_t)(b * NKV + kvh)) * HD + l32 * 4);
    const float4 vnew = *(const float4*)(xqkv + (size_t)b * NQKV + (NH + NKV + kvh) * HD + l32 * 4);
    float sst[GRP], snw[GRP];
#pragma unroll
    for (int g = 0; g < GRP; ++g) {
      sst[g] = q[g].x * kst.x + q[g].y * kst.y + q[g].z * kst.z + q[g].w * kst.w;
      snw[g] = q[g].x * knew.x + q[g].y * knew.y + q[g].z * knew.z + q[g].w * knew.w;
    }
#pragma unroll
    for (int off = 16; off > 0; off >>= 1) {
#pragma unroll
      for (int g = 0; g < GRP; ++g) {
        sst[g] += __shfl_xor(sst[g], off);
        snw[g] += __shfl_xor(snw[g], off);
      }
    }
#pragma unroll
    for (int g = 0; g < GRP; ++g) {
      float wst = fast_exp2(sst[g]);
      float wnw = fast_exp2(snw[g]);
      l[g] += wnw - wst;
      acc[g].x += wnw * vnew.x - wst * vst.x;
      acc[g].y += wnw * vnew.y - wst * vst.y;
      acc[g].z += wnw * vnew.z - wst * vst.z;
      acc[g].w += wnw * vnew.w - wst * vst.w;
    }
  }

  // combine the two halves of the wave
#pragma unroll
  for (int g = 0; g < GRP; ++g) {
    l[g] += __shfl_xor(l[g], 32);
    acc[g].x += __shfl_xor(acc[g].x, 32);
    acc[g].y += __shfl_xor(acc[g].y, 32);
    acc[g].z += __shfl_xor(acc[g].z, 32);
    acc[g].w += __shfl_xor(acc[g].w, 32);
  }

  // combine the 4 waves via LDS
  __shared__ float red_l[4][GRP];
  __shared__ float red_o[4][GRP][HD];
  if (lane == 0) {
#pragma unroll
    for (int g = 0; g < GRP; ++g) red_l[wave][g] = l[g];
  }
  if (half == 0) {
#pragma unroll
    for (int g = 0; g < GRP; ++g)
      *(float4*)&red_o[wave][g][l32 * 4] = acc[g];
  }
  __syncthreads();

  const size_t pc = (size_t)pair * SPLIT + chunk;
  for (int idx = tid; idx < GRP * HD; idx += 256) {
    int g = idx >> 7, d = idx & 127;
    float o = red_o[0][g][d] + red_o[1][g][d] + red_o[2][g][d] + red_o[3][g][d];
    o_part[(pc * GRP + g) * HD + d] = o;
  }
  if (tid < GRP) {
    l_part[pc * GRP + tid] =
        red_l[0][tid] + red_l[1][tid] + red_l[2][tid] + red_l[3][tid];
  }
}

// ---------------------------------------------------------------------------
// Combine the SPLIT chunk partials -> attn_out[b][n*128 + d]
// ---------------------------------------------------------------------------
__global__ __launch_bounds__(128)
void attn_combine(const float* __restrict__ o_part, const float* __restrict__ l_part,
                  float* __restrict__ attn_out) {
  const int bid = blockIdx.x;   // b*32 + n
  const int b = bid >> 5, n = bid & 31;
  const int pair = b * NKV + (n >> 2);
  const int g = n & 3;
  const int d = threadIdx.x;

  float lsum = 0.f, osum = 0.f;
#pragma unroll
  for (int c = 0; c < SPLIT; ++c) {
    size_t pc = (size_t)pair * SPLIT + c;
    lsum += l_part[pc * GRP + g];
    osum += o_part[(pc * GRP + g) * HD + d];
  }
  attn_out[(size_t)b * DIM + n * HD + d] = osum / lsum;
}

// ---------------------------------------------------------------------------
extern "C" void kernel_launch(void* const* d_in, const int* in_sizes, int n_in,
                              void* d_out, int out_size, void* d_ws, size_t ws_size,
                              hipStream_t stream) {
  (void)in_sizes; (void)n_in; (void)out_size; (void)ws_size;

  const float* x    = (const float*)d_in[0];  // [1,1,32,4096]
  const float* wqkv = (const float*)d_in[1];  // [4096,6144]
  const float* wo   = (const float*)d_in[2];  // [4096,4096]
  const float* rot  = (const float*)d_in[3];  // [128,128]
  const float* ck   = (const float*)d_in[4];  // [8,32,4096,128]
  const float* cv   = (const float*)d_in[5];  // [8,32,4096,128]
  const int*   sp   = (const int*)d_in[6];    // scalar
  float* out = (float*)d_out;                 // [32,4096]

  float* ws       = (float*)d_ws;
  // part (KS*B*NQKV = 6.29M floats) is dead between reduce#1 and gemv#2,
  // so o_part (B*NKV*SPLIT*GRP*HD = 2.1M floats) aliases it.
  float* part     = ws;
  float* o_part   = ws;
  float* xqkv     = part + (size_t)KS * B * NQKV;
  float* qrot     = xqkv + (size_t)B * NQKV;
  float* krot     = qrot + (size_t)B * NH * HD;
  float* l_part   = krot + (size_t)B * NKV * HD;
  float* attn_out = l_part + (size_t)B * NKV * SPLIT * GRP;
  // total ~6.95M floats ≈ 28 MB of workspace

  // 1) xqkv = x @ wqkv  (split-K partials, then reduce)
  gemv32_partial<<<dim3(NQKV / 256, KS), 256, 0, stream>>>(x, wqkv, part, DIM, NQKV);
  reduce_partials<<<(B * NQKV) / 256, 256, 0, stream>>>(part, xqkv, B * NQKV);

  // 2) rotary on q (scaled; exp2 base folded in) and k
  rotary_kernel<<<dim3(B, NH + NKV), 128, 0, stream>>>(xqkv, rot, qrot, krot);

  // 3) flash-decode attention (stale loop + post-correction)
  attn_partial<<<dim3(B * NKV, SPLIT), 256, 0, stream>>>(ck, cv, qrot, krot, xqkv,
                                                         sp, o_part, l_part);
  attn_combine<<<B * NH, 128, 0, stream>>>(o_part, l_part, attn_out);

  // 4) dense = attn_out @ wo
  gemv32_partial<<<dim3(DIM / 256, KS), 256, 0, stream>>>(attn_out, wo, part, DIM, DIM);
  reduce_partials<<<(B * DIM) / 256, 256, 0, stream>>>(part, out, B * DIM);
}